// Round 2
// baseline (59.731 us; speedup 1.0000x reference)
//
#include <hip/hip_runtime.h>
#include <math.h>

// Problem constants (from reference): B=8, N=512, T=8192, D=256.
#define BB 8
#define NN 512
#define TT 8192
#define DD 256
#define FR 4  // frames per block in out_kernel

// Kernel 1: per-batch inclusive scan of durations -> segment start frames.
// One block per batch, NN threads. Hillis-Steele in LDS.
__global__ void scan_kernel(const int* __restrict__ dur, int* __restrict__ start) {
    __shared__ int s[NN];
    const int b = blockIdx.x;
    const int n = threadIdx.x;
    const int d = dur[b * NN + n];
    s[n] = d;
    for (int off = 1; off < NN; off <<= 1) {
        __syncthreads();
        const int v = (n >= off) ? s[n - off] : 0;
        __syncthreads();
        s[n] += v;
    }
    // inclusive cumsum - own duration = start frame of segment n
    start[b * NN + n] = s[n] - d;
}

// Kernel 2: fill frame->segment map and positions output.
// One thread per (b, n); writes seg_id and positions for its frame range.
//
// fp32 boundary subtlety (replicates reference exactly): at t == start,
// t - c == -dur/2 exactly; reference adds 1e-6f in fp32. If dur/2 > 32 the
// half-ULP exceeds 1e-6 and the nudge rounds away -> |v| < dur/2 is FALSE ->
// the start frame of a large segment is covered by NO segment (weights col
// all zero, out row zero, positions = t).
__global__ void fill_kernel(const int* __restrict__ dur,
                            const int* __restrict__ start,
                            int* __restrict__ seg_id,
                            float* __restrict__ positions) {
    const int idx = blockIdx.x * blockDim.x + threadIdx.x;
    if (idx >= BB * NN) return;
    const int b  = idx >> 9;          // / NN
    const int n  = idx & (NN - 1);
    const int st = start[idx];
    const int du = dur[idx];
    const int base = b * TT;

    // Exact fp32 replication of the reference's test at t = st:
    //   v = (t - c) + 1e-6f  with  t - c = -dur/2 exact
    const float h  = 0.5f * (float)du;
    const float v0 = 1e-6f - h;            // one fp32 rounding, same as ref
    const bool  cov = fabsf(v0) < h;

    seg_id[base + st]    = cov ? n : -1;
    positions[base + st] = cov ? 0.0f : (float)st;

    for (int t = st + 1; t < st + du; ++t) {
        seg_id[base + t]    = n;
        positions[base + t] = (float)(t - st);
    }
}

// Kernel 3: out[b,t,:] = x[b, seg_id[b,t], :] (zeros if uncovered).
// 256 threads = FR frames, 64 threads/frame, float4 per thread.
__global__ void out_kernel(const float* __restrict__ x,
                           const int* __restrict__ seg_id,
                           float* __restrict__ outp) {
    const int blk  = blockIdx.x;
    const int b    = blk / (TT / FR);
    const int tile = blk % (TT / FR);
    const int f    = threadIdx.x >> 6;
    const int d4   = (threadIdx.x & 63) << 2;
    const int t    = tile * FR + f;
    const int seg  = seg_id[b * TT + t];
    float4 v = make_float4(0.f, 0.f, 0.f, 0.f);
    if (seg >= 0)
        v = *(const float4*)(x + (((size_t)b * NN + seg) * DD + d4));
    *(float4*)(outp + (((size_t)b * TT + t) * DD + d4)) = v;
}

// Kernel 4: weights[b,n,t] = (seg_id[b,t] == n). Full write every call
// (harness poisons d_out once; we must write every element). seg=-1 matches
// no n, giving the all-zero column for uncovered frames.
__global__ void weights_kernel(const int* __restrict__ seg_id,
                               float* __restrict__ w) {
    const int idx = blockIdx.x * blockDim.x + threadIdx.x;
    const int tq  = idx & (TT / 4 - 1);       // 11 bits
    const int n   = (idx >> 11) & (NN - 1);   // 9 bits
    const int b   = idx >> 20;
    const int t   = tq << 2;
    const int4 sg = *(const int4*)(seg_id + b * TT + t);
    float4 o;
    o.x = (sg.x == n) ? 1.0f : 0.0f;
    o.y = (sg.y == n) ? 1.0f : 0.0f;
    o.z = (sg.z == n) ? 1.0f : 0.0f;
    o.w = (sg.w == n) ? 1.0f : 0.0f;
    *(float4*)(w + ((size_t)idx << 2)) = o;
}

extern "C" void kernel_launch(void* const* d_in, const int* in_sizes, int n_in,
                              void* d_out, int out_size, void* d_ws, size_t ws_size,
                              hipStream_t stream) {
    const float* x  = (const float*)d_in[0];
    const int* dur  = (const int*)d_in[1];

    // Output layout: positions [B,T] | out [B,T,D] | weights [B,N,T]
    float* pos  = (float*)d_out;
    float* outp = pos + (size_t)BB * TT;
    float* w    = outp + (size_t)BB * TT * DD;

    // Workspace: start [B*N] ints, seg_id [B*T] ints (~272 KB)
    int* start = (int*)d_ws;
    int* seg   = start + BB * NN;

    scan_kernel<<<BB, NN, 0, stream>>>(dur, start);
    fill_kernel<<<(BB * NN) / 256, 256, 0, stream>>>(dur, start, seg, pos);
    out_kernel<<<(BB * TT) / FR, 256, 0, stream>>>(x, seg, outp);
    weights_kernel<<<(BB * NN * TT / 4) / 256, 256, 0, stream>>>(seg, w);
}

// Round 3
// 54.704 us; speedup vs baseline: 1.0919x; 1.0919x over previous
//
#include <hip/hip_runtime.h>
#include <math.h>

// Problem constants (from reference): B=8, N=512, T=8192, D=256.
#define BB 8
#define NN 512
#define TT 8192
#define DD 256
#define FR 4  // frames per block in the out-gather part

// ---------------------------------------------------------------------------
// Kernel 1 (setup): one block per batch, NN=512 threads.
//   a) LDS Hillis-Steele scan of durations -> segment end frames
//   b) per-segment fp32 coverage flag (replicates reference boundary rounding)
//   c) frame-parallel fill of seg_id + positions via LDS binary search
//      (coalesced writes, 512 threads/batch)
//
// fp32 boundary subtlety (verified round 2): at t == start, t - c == -dur/2
// exactly; reference adds 1e-6f. For dur/2 >= 32 the half-ULP exceeds 1e-6 so
// the sum rounds back to dur/2 -> start frame of that segment is covered by
// NO segment (weights column all zero, out row zero, positions = t).
// ---------------------------------------------------------------------------
__global__ void setup_kernel(const int* __restrict__ dur,
                             int* __restrict__ seg_id,
                             float* __restrict__ positions) {
    __shared__ int s_end[NN + 1];   // s_end[n] = start of segment n; s_end[NN] = T
    __shared__ int s_cov[NN];       // 1 if segment's start frame is covered
    const int b = blockIdx.x;
    const int n = threadIdx.x;

    const int d = dur[b * NN + n];
    // inclusive scan in s_end[1..NN]
    s_end[n + 1] = d;
    if (n == 0) s_end[0] = 0;
    int acc = d;
    for (int off = 1; off < NN; off <<= 1) {
        __syncthreads();
        const int v = (n >= off) ? s_end[n + 1 - off] : 0;
        __syncthreads();
        acc += v;
        s_end[n + 1] = acc;
    }
    // coverage of the start frame: v0 = (t - c) + 1e-6f with t - c = -dur/2
    const float h = 0.5f * (float)d;
    s_cov[n] = (fabsf(1e-6f - h) < h) ? 1 : 0;
    __syncthreads();

    const int base = b * TT;
    for (int t = n; t < TT; t += NN) {
        // first segment whose end > t  <=>  s_end[lo] <= t < s_end[lo+1]
        int lo = 0, hi = NN - 1;
        while (lo < hi) {
            const int mid = (lo + hi) >> 1;
            if (t < s_end[mid + 1]) hi = mid; else lo = mid + 1;
        }
        const int st = s_end[lo];
        int   sg;
        float pv;
        if (t == st && !s_cov[lo]) { sg = -1; pv = (float)t; }
        else                       { sg = lo; pv = (float)(t - st); }
        seg_id[base + t]    = sg;
        positions[base + t] = pv;
    }
}

// ---------------------------------------------------------------------------
// Kernel 2 (bigwrite): merged grid.
//   blocks [0, OUT_BLOCKS):             out[b,t,:] = x[b, seg_id[b,t], :]
//   blocks [OUT_BLOCKS, +W_BLOCKS):     weights[b,n,t] = (seg_id[b,t] == n)
// Both phases are pure streaming writes; merging removes the dispatch gap.
// ---------------------------------------------------------------------------
#define OUT_BLOCKS (BB * TT / FR)                 // 16384
#define W_BLOCKS   (BB * NN * TT / 4 / 256)       // 32768

__global__ void bigwrite_kernel(const float* __restrict__ x,
                                const int* __restrict__ seg_id,
                                float* __restrict__ outp,
                                float* __restrict__ w) {
    if (blockIdx.x < OUT_BLOCKS) {
        // out gather: 64 threads/frame, float4 per thread (16B, coalesced)
        const int blk  = blockIdx.x;
        const int b    = blk / (TT / FR);
        const int tile = blk % (TT / FR);
        const int f    = threadIdx.x >> 6;
        const int d4   = (threadIdx.x & 63) << 2;
        const int t    = tile * FR + f;
        const int seg  = seg_id[b * TT + t];
        float4 v = make_float4(0.f, 0.f, 0.f, 0.f);
        if (seg >= 0)
            v = *(const float4*)(x + (((size_t)b * NN + seg) * DD + d4));
        *(float4*)(outp + (((size_t)b * TT + t) * DD + d4)) = v;
    } else {
        // weights: idx = (b<<20)|(n<<11)|tq, 4 t's per thread (float4 store).
        // seg=-1 matches no n -> all-zero column for uncovered frames.
        const int idx = (blockIdx.x - OUT_BLOCKS) * blockDim.x + threadIdx.x;
        const int tq  = idx & (TT / 4 - 1);       // 11 bits
        const int n   = (idx >> 11) & (NN - 1);   // 9 bits
        const int b   = idx >> 20;
        const int t   = tq << 2;
        const int4 sg = *(const int4*)(seg_id + b * TT + t);
        float4 o;
        o.x = (sg.x == n) ? 1.0f : 0.0f;
        o.y = (sg.y == n) ? 1.0f : 0.0f;
        o.z = (sg.z == n) ? 1.0f : 0.0f;
        o.w = (sg.w == n) ? 1.0f : 0.0f;
        *(float4*)(w + ((size_t)idx << 2)) = o;
    }
}

extern "C" void kernel_launch(void* const* d_in, const int* in_sizes, int n_in,
                              void* d_out, int out_size, void* d_ws, size_t ws_size,
                              hipStream_t stream) {
    const float* x  = (const float*)d_in[0];
    const int* dur  = (const int*)d_in[1];

    // Output layout: positions [B,T] | out [B,T,D] | weights [B,N,T]
    float* pos  = (float*)d_out;
    float* outp = pos + (size_t)BB * TT;
    float* w    = outp + (size_t)BB * TT * DD;

    // Workspace: seg_id [B*T] ints (256 KB)
    int* seg = (int*)d_ws;

    setup_kernel<<<BB, NN, 0, stream>>>(dur, seg, pos);
    bigwrite_kernel<<<OUT_BLOCKS + W_BLOCKS, 256, 0, stream>>>(x, seg, outp, w);
}

// Round 4
// 45.222 us; speedup vs baseline: 1.3208x; 1.2097x over previous
//
#include <hip/hip_runtime.h>
#include <math.h>

// Problem constants (from reference): B=8, N=512, T=8192, D=256.
#define BB 8
#define NN 512
#define TT 8192
#define DD 256

// float4-granular work items in the big kernel:
//   out:     BB*TT*DD/4 = 4,194,304  (one frame = 64 consecutive items = 1 wave)
//   weights: BB*NN*TT/4 = 8,388,608
#define OUT_V4   (BB * TT * (DD / 4))
#define W_V4     (BB * NN * (TT / 4))
#define TOTAL_V4 (OUT_V4 + W_V4)

#define BW_BLOCKS 2048
#define BW_THREADS 256

// ---------------------------------------------------------------------------
// Kernel 1 (setup): 64 blocks = 8 batches x 8 frame-chunks, 512 threads.
// Each block redundantly scans its batch's 512 durations in LDS (cheap),
// then fills seg_id + positions for its 1024-frame chunk via binary search.
//
// fp32 boundary subtlety (verified round 2): at t == start, t - c == -dur/2
// exactly; reference adds 1e-6f. For dur/2 >= 32 the half-ULP exceeds 1e-6 so
// the sum rounds back to dur/2 -> that start frame is covered by NO segment
// (weights column all zero, out row zero, positions = t).
// ---------------------------------------------------------------------------
__global__ void setup_kernel(const int* __restrict__ dur,
                             int* __restrict__ seg_id,
                             float* __restrict__ positions) {
    __shared__ int s_end[NN + 1];   // s_end[n] = start of segment n; s_end[NN] = T
    __shared__ int s_cov[NN];       // 1 if segment's start frame is covered
    const int b     = blockIdx.x >> 3;
    const int chunk = blockIdx.x & 7;
    const int n     = threadIdx.x;

    const int d = dur[b * NN + n];
    s_end[n + 1] = d;
    if (n == 0) s_end[0] = 0;
    int acc = d;
    for (int off = 1; off < NN; off <<= 1) {
        __syncthreads();
        const int v = (n >= off) ? s_end[n + 1 - off] : 0;
        __syncthreads();
        acc += v;
        s_end[n + 1] = acc;
    }
    const float h = 0.5f * (float)d;
    s_cov[n] = (fabsf(1e-6f - h) < h) ? 1 : 0;
    __syncthreads();

    const int base = b * TT;
    const int t0   = chunk * (TT / 8);
    for (int t = t0 + n; t < t0 + TT / 8; t += NN) {
        int lo = 0, hi = NN - 1;          // find lo: s_end[lo] <= t < s_end[lo+1]
        while (lo < hi) {
            const int mid = (lo + hi) >> 1;
            if (t < s_end[mid + 1]) hi = mid; else lo = mid + 1;
        }
        const int st = s_end[lo];
        int   sg;
        float pv;
        if (t == st && !s_cov[lo]) { sg = -1; pv = (float)t; }
        else                       { sg = lo; pv = (float)(t - st); }
        seg_id[base + t]    = sg;
        positions[base + t] = pv;
    }
}

// ---------------------------------------------------------------------------
// Kernel 2 (bigwrite): grid-stride over all float4 items.
//   items [0, OUT_V4):        out[b,t,:] = x[b, seg_id[b,t], :]
//   items [OUT_V4, TOTAL_V4): weights[b,n,t] = (seg_id[b,t] == n)
// 2048 blocks x 256 threads, ~24 items/thread — block-count capped so block
// turnover doesn't gate BW (round-3 lesson: 49k tiny blocks cost ~25 us).
// ---------------------------------------------------------------------------
__global__ void __launch_bounds__(BW_THREADS)
bigwrite_kernel(const float* __restrict__ x,
                const int* __restrict__ seg_id,
                float* __restrict__ outp,
                float* __restrict__ w) {
    const int stride = BW_BLOCKS * BW_THREADS;
    for (int i = blockIdx.x * BW_THREADS + threadIdx.x; i < TOTAL_V4; i += stride) {
        if (i < OUT_V4) {
            // out gather: 64 consecutive items = one frame (one wave), 16B/lane
            const int d4  = (i & 63) << 2;
            const int t   = (i >> 6) & (TT - 1);
            const int b   = i >> 19;
            const int seg = seg_id[b * TT + t];
            float4 v = make_float4(0.f, 0.f, 0.f, 0.f);
            if (seg >= 0)
                v = *(const float4*)(x + (((size_t)b * NN + seg) * DD + d4));
            *(float4*)(outp + (((size_t)b * TT + t) * DD + d4)) = v;
        } else {
            // weights: widx = (b<<20)|(n<<11)|tq ; 4 t's per item.
            // seg=-1 matches no n -> all-zero column for uncovered frames.
            const int widx = i - OUT_V4;
            const int tq   = widx & (TT / 4 - 1);
            const int n    = (widx >> 11) & (NN - 1);
            const int b    = widx >> 20;
            const int t    = tq << 2;
            const int4 sg  = *(const int4*)(seg_id + b * TT + t);
            float4 o;
            o.x = (sg.x == n) ? 1.0f : 0.0f;
            o.y = (sg.y == n) ? 1.0f : 0.0f;
            o.z = (sg.z == n) ? 1.0f : 0.0f;
            o.w = (sg.w == n) ? 1.0f : 0.0f;
            *(float4*)(w + ((size_t)widx << 2)) = o;
        }
    }
}

extern "C" void kernel_launch(void* const* d_in, const int* in_sizes, int n_in,
                              void* d_out, int out_size, void* d_ws, size_t ws_size,
                              hipStream_t stream) {
    const float* x  = (const float*)d_in[0];
    const int* dur  = (const int*)d_in[1];

    // Output layout: positions [B,T] | out [B,T,D] | weights [B,N,T]
    float* pos  = (float*)d_out;
    float* outp = pos + (size_t)BB * TT;
    float* w    = outp + (size_t)BB * TT * DD;

    // Workspace: seg_id [B*T] ints (256 KB)
    int* seg = (int*)d_ws;

    setup_kernel<<<BB * 8, NN, 0, stream>>>(dur, seg, pos);
    bigwrite_kernel<<<BW_BLOCKS, BW_THREADS, 0, stream>>>(x, seg, outp, w);
}